// Round 1
// 133.920 us; speedup vs baseline: 1.0951x; 1.0951x over previous
//
#include <hip/hip_runtime.h>
#include <hip/hip_bf16.h>
#include <math.h>

#define C_IN  64
#define HID   128
#define C_OUT 64

typedef __attribute__((ext_vector_type(8))) short s16x8;   // 8 bf16 (4 VGPR)
typedef __attribute__((ext_vector_type(4))) float f32x4;   // MFMA acc
typedef __attribute__((ext_vector_type(2))) float f32x2;   // packed-fp32 pair

// ---------------------------------------------------------------------------
// Fast GELU (tanh form), PACKED 2-wide. Bit-identical math to prior rounds.
// ---------------------------------------------------------------------------
__device__ __forceinline__ f32x2 gelu2(f32x2 x) {
    f32x2 t  = x * x;                                   // pk_mul
    f32x2 p  = t * 0.10294455f + 2.30211462f;           // pk_fma
    f32x2 xp = x * p;                                   // pk_mul
    f32x2 E;
    E.x = __builtin_amdgcn_exp2f(xp.x);                 // trans
    E.y = __builtin_amdgcn_exp2f(xp.y);                 // trans
    f32x2 Ep = E + 1.0f;                                // pk_add
    f32x2 r;
    r.x = __builtin_amdgcn_rcpf(Ep.x);                  // trans
    r.y = __builtin_amdgcn_rcpf(Ep.y);                  // trans
    return x - x * r;                                   // pk_fma
}

__device__ __forceinline__ float4 fma4(float s, float4 w, float4 acc) {
    acc.x = fmaf(s, w.x, acc.x); acc.y = fmaf(s, w.y, acc.y);
    acc.z = fmaf(s, w.z, acc.z); acc.w = fmaf(s, w.w, acc.w);
    return acc;
}

__device__ __forceinline__ unsigned pk_bf16(float lo, float hi) {
    union { __hip_bfloat162 v; unsigned u; } cv;
    cv.v = __float22bfloat162_rn(make_float2(lo, hi));
    return cv.u;
}
// unpack dword of 2x bf16 -> f32x2 (consecutive VGPRs -> pk-friendly)
__device__ __forceinline__ f32x2 unpk2(unsigned p) {
    union { unsigned u; float f; } lo, hi;
    lo.u = p << 16; hi.u = p & 0xffff0000u;
    f32x2 v; v.x = lo.f; v.y = hi.f; return v;
}

// ---------------------------------------------------------------------------
// Kernel 1: per-node factored first linear ([50000x64] @ [64x256] GEMM).
//   A16[n][h] = bf16( X[n][:] . W1[0:64,h] )       (gathered per-edge)
//   B  [n][h] =       X[n][:] . W1[64:128,h] + b1  (read per-row, f32)
// Block 0 additionally transposes W2 -> W2T[c][k] bf16 for the MFMA kernel.
// ---------------------------------------------------------------------------
#define K1_NODES 64

__global__ __launch_bounds__(512, 2) void precompute_ab(
    const float* __restrict__ X, const float* __restrict__ W1,
    const float* __restrict__ b1, const float* __restrict__ W2,
    unsigned* __restrict__ A16, float* __restrict__ B,
    unsigned short* __restrict__ W2T, int N)
{
    __shared__ float W1s[2 * C_IN * HID];     // 64 KiB
    __shared__ float xs[K1_NODES * C_IN];     // 16 KiB
    int tid = threadIdx.x;

    for (int i = tid; i < (2 * C_IN * HID) / 4; i += 512)
        ((float4*)W1s)[i] = ((const float4*)W1)[i];

    int base = blockIdx.x * K1_NODES;
    int nLoc = min(K1_NODES, N - base);
    for (int i = tid; i < nLoc * (C_IN / 4); i += 512)
        ((float4*)xs)[i] = ((const float4*)(X + (size_t)base * C_IN))[i];

    if (blockIdx.x == 0) {                     // one-time W2 -> bf16 k-major
        for (int i = tid; i < C_OUT * HID; i += 512) {
            int c = i >> 7, k = i & (HID - 1);
            W2T[i] = (unsigned short)pk_bf16(W2[k * C_OUT + c], 0.f);
        }
    }
    __syncthreads();

    int quad = (tid & 31) * 4;    // h-quad 0,4,...,124
    int slot = tid >> 5;          // 0..15, owns nodes 4*slot .. 4*slot+3
    int s0   = slot * 4;
    if (s0 >= nLoc) return;

    float4 a0 = {}, a1 = {}, a2 = {}, a3 = {};
    float4 b0 = {}, b1r = {}, b2r = {}, b3 = {};

    const float* xr0 = xs + (s0 + 0) * C_IN;
    const float* xr1 = xs + (s0 + 1) * C_IN;
    const float* xr2 = xs + (s0 + 2) * C_IN;
    const float* xr3 = xs + (s0 + 3) * C_IN;

#define K1STEP(c, CMP)                                                      \
    do {                                                                    \
        float4 wa = *(const float4*)&W1s[(c) * HID + quad];                 \
        float4 wb = *(const float4*)&W1s[((c) + C_IN) * HID + quad];        \
        a0 = fma4(xv0.CMP, wa, a0); b0  = fma4(xv0.CMP, wb, b0);            \
        a1 = fma4(xv1.CMP, wa, a1); b1r = fma4(xv1.CMP, wb, b1r);           \
        a2 = fma4(xv2.CMP, wa, a2); b2r = fma4(xv2.CMP, wb, b2r);           \
        a3 = fma4(xv3.CMP, wa, a3); b3  = fma4(xv3.CMP, wb, b3);            \
    } while (0)

#pragma unroll 1
    for (int c4 = 0; c4 < C_IN; c4 += 4) {
        float4 xv0 = *(const float4*)&xr0[c4];
        float4 xv1 = *(const float4*)&xr1[c4];
        float4 xv2 = *(const float4*)&xr2[c4];
        float4 xv3 = *(const float4*)&xr3[c4];
        K1STEP(c4 + 0, x);
        K1STEP(c4 + 1, y);
        K1STEP(c4 + 2, z);
        K1STEP(c4 + 3, w);
    }
#undef K1STEP

    float4 bb = *(const float4*)(b1 + quad);
    b0.x += bb.x;  b0.y += bb.y;  b0.z += bb.z;  b0.w += bb.w;
    b1r.x += bb.x; b1r.y += bb.y; b1r.z += bb.z; b1r.w += bb.w;
    b2r.x += bb.x; b2r.y += bb.y; b2r.z += bb.z; b2r.w += bb.w;
    b3.x += bb.x;  b3.y += bb.y;  b3.z += bb.z;  b3.w += bb.w;

    int adw = (base + s0) * (HID / 2) + (quad >> 1);
    size_t boff = (size_t)(base + s0) * HID + quad;
    if (s0 + 0 < nLoc) {
        uint2 u = { pk_bf16(a0.x, a0.y), pk_bf16(a0.z, a0.w) };
        *(uint2*)(A16 + adw) = u;              *(float4*)(B + boff) = b0;
    }
    if (s0 + 1 < nLoc) {
        uint2 u = { pk_bf16(a1.x, a1.y), pk_bf16(a1.z, a1.w) };
        *(uint2*)(A16 + adw + HID / 2) = u;    *(float4*)(B + boff + HID) = b1r;
    }
    if (s0 + 2 < nLoc) {
        uint2 u = { pk_bf16(a2.x, a2.y), pk_bf16(a2.z, a2.w) };
        *(uint2*)(A16 + adw + HID) = u;        *(float4*)(B + boff + 2 * HID) = b2r;
    }
    if (s0 + 3 < nLoc) {
        uint2 u = { pk_bf16(a3.x, a3.y), pk_bf16(a3.z, a3.w) };
        *(uint2*)(A16 + adw + 3 * (HID / 2)) = u; *(float4*)(B + boff + 3 * HID) = b3;
    }
}

// ---------------------------------------------------------------------------
// Kernel 2 (REWRITTEN): latency-hiding edge aggregation.
//   * 2 edges per gather instruction: 32 lanes/edge, dwordx2/lane (4 dims).
//   * 64-edge index chunk loaded ONCE coalesced into lanes; per-pair indices
//     broadcast in-register via __shfl (ds_bpermute) -> no memory on the
//     index critical path.
//   * 8-edge groups software-pipelined one group ahead with statically named
//     double buffers (A0..A3 / B0..B3) -> gathers in flight under GELU.
//   * half-wave accumulators merged with __shfl_xor(...,32) at row end.
// ---------------------------------------------------------------------------
#define EA_WAVES 2

#define EA_ISSUE(P0,P1,P2,P3, g) do { int _s8 = ((g) << 3) + half;            \
    int _i0 = __shfl(idx, _s8);                                               \
    int _i1 = __shfl(idx, _s8 + 2);                                           \
    int _i2 = __shfl(idx, _s8 + 4);                                           \
    int _i3 = __shfl(idx, _s8 + 6);                                           \
    P0 = *(const uint2*)(A8 + ((((unsigned)_i0) << 8) | lb));                 \
    P1 = *(const uint2*)(A8 + ((((unsigned)_i1) << 8) | lb));                 \
    P2 = *(const uint2*)(A8 + ((((unsigned)_i2) << 8) | lb));                 \
    P3 = *(const uint2*)(A8 + ((((unsigned)_i3) << 8) | lb));                 \
} while (0)

#define EA_PROC1(P) do {                                                      \
    acc01 += gelu2(unpk2(P.x) + bb01);                                        \
    acc23 += gelu2(unpk2(P.y) + bb23); } while (0)

#define EA_PROC1M(P, p) do {                                                  \
    float _mk = ((((p) << 1) + half) < m) ? 1.f : 0.f;                        \
    acc01 += gelu2(unpk2(P.x) + bb01) * _mk;                                  \
    acc23 += gelu2(unpk2(P.y) + bb23) * _mk; } while (0)

#define EA_PROCG(P0,P1,P2,P3, g) do {                                         \
    if ((((g) + 1) << 3) <= m) { EA_PROC1(P0); EA_PROC1(P1);                  \
                                 EA_PROC1(P2); EA_PROC1(P3); }                \
    else { int _p = (g) << 2;                                                 \
           EA_PROC1M(P0, _p);                                                 \
           if (((_p + 1) << 1) < m) EA_PROC1M(P1, _p + 1);                    \
           if (((_p + 2) << 1) < m) EA_PROC1M(P2, _p + 2);                    \
           if (((_p + 3) << 1) < m) EA_PROC1M(P3, _p + 3); } } while (0)

__global__ __launch_bounds__(128) void edge_agg(
    const unsigned* __restrict__ A16, const float* __restrict__ B,
    const int* __restrict__ nbr, const int* __restrict__ rs,
    unsigned* __restrict__ Hout, int N, int E, int G)
{
    int wave = threadIdx.x >> 6, lane = threadIdx.x & 63;
    int half = lane >> 5, l5 = lane & 31;
    const char* A8 = (const char*)A16;
    unsigned lb = (unsigned)(l5 << 3);          // byte offset within row
    int b = blockIdx.x;

    int t0 = (int)(((long long)E * b) / G);
    int r0, r1;
    {   // r0 = first row with rs[row] >= t0
        int lo = 0, hi = N;
        while (lo < hi) { int mm = (lo + hi) >> 1; if (rs[mm] < t0) lo = mm + 1; else hi = mm; }
        r0 = lo;
    }
    if (b == G - 1) r1 = N;
    else {
        int t1 = (int)(((long long)E * (b + 1)) / G);
        int lo = r0, hi = N;
        while (lo < hi) { int mm = (lo + hi) >> 1; if (rs[mm] < t1) lo = mm + 1; else hi = mm; }
        r1 = lo;
    }

    for (int row = r0 + wave; row < r1; row += EA_WAVES) {
        int s = rs[row], e = rs[row + 1];
        int cnt = e - s;

        // 4 dims per lane; both halves read the same B row slice
        float4 bb4 = *(const float4*)(B + (size_t)row * HID + l5 * 4);
        f32x2 bb01, bb23;
        bb01.x = bb4.x; bb01.y = bb4.y; bb23.x = bb4.z; bb23.y = bb4.w;
        f32x2 acc01 = {0.f, 0.f}, acc23 = {0.f, 0.f};

        for (int cs = s; cs < e; cs += 64) {
            int m = min(64, e - cs);
            int idx = nbr[cs + min(lane, m - 1)];   // whole chunk's indices in regs
            int ng = (m + 7) >> 3;                  // 8-edge groups (last may be partial)

            uint2 A0, A1, A2, A3, B0, B1, B2, B3;

            EA_ISSUE(A0, A1, A2, A3, 0);
            int g = 0;
            for (;;) {
                if (g + 1 < ng) { EA_ISSUE(B0, B1, B2, B3, g + 1);
                                  EA_PROCG(A0, A1, A2, A3, g); ++g; }
                else            { EA_PROCG(A0, A1, A2, A3, g); break; }
                if (g + 1 < ng) { EA_ISSUE(A0, A1, A2, A3, g + 1);
                                  EA_PROCG(B0, B1, B2, B3, g); ++g; }
                else            { EA_PROCG(B0, B1, B2, B3, g); break; }
            }
        }

        // merge the two half-wave edge partial sums
        acc01.x += __shfl_xor(acc01.x, 32);
        acc01.y += __shfl_xor(acc01.y, 32);
        acc23.x += __shfl_xor(acc23.x, 32);
        acc23.y += __shfl_xor(acc23.y, 32);

        if (half == 0) {
            float sc = (cnt > 0) ? 1.f / (float)cnt : 0.f;
            uint2 o = { pk_bf16(acc01.x * sc, acc01.y * sc),
                        pk_bf16(acc23.x * sc, acc23.y * sc) };
            ((uint2*)(Hout + (size_t)row * (HID / 2)))[l5] = o;
        }
    }
}

#undef EA_ISSUE
#undef EA_PROC1
#undef EA_PROC1M
#undef EA_PROCG

// ---------------------------------------------------------------------------
// Kernel 3: out = Hbar @ W2 + b2 via MFMA (bf16 in, f32 out). Unchanged.
// ---------------------------------------------------------------------------
__global__ __launch_bounds__(256) void h_w2_mfma(
    const unsigned short* __restrict__ H, const unsigned short* __restrict__ W2T,
    const float* __restrict__ b2, const int* __restrict__ rs,
    float* __restrict__ out, int N)
{
    int wave = threadIdx.x >> 6, lane = threadIdx.x & 63;
    int base = (blockIdx.x * 4 + wave) * 16;
    if (base >= N) return;

    int r16 = lane & 15;
    int kg  = lane >> 4;

    const unsigned short* hrow = H + (size_t)(base + r16) * HID + kg * 8;
    const unsigned short* wc0  = W2T + (size_t)(0 * 16 + r16) * HID + kg * 8;
    const unsigned short* wc1  = W2T + (size_t)(1 * 16 + r16) * HID + kg * 8;
    const unsigned short* wc2  = W2T + (size_t)(2 * 16 + r16) * HID + kg * 8;
    const unsigned short* wc3  = W2T + (size_t)(3 * 16 + r16) * HID + kg * 8;

    f32x4 acc0 = {0.f, 0.f, 0.f, 0.f};
    f32x4 acc1 = acc0, acc2 = acc0, acc3 = acc0;

#pragma unroll
    for (int kk = 0; kk < 4; ++kk) {
        s16x8 a  = *(const s16x8*)(hrow + kk * 32);
        s16x8 f0 = *(const s16x8*)(wc0 + kk * 32);
        s16x8 f1 = *(const s16x8*)(wc1 + kk * 32);
        s16x8 f2 = *(const s16x8*)(wc2 + kk * 32);
        s16x8 f3 = *(const s16x8*)(wc3 + kk * 32);
        acc0 = __builtin_amdgcn_mfma_f32_16x16x32_bf16(a, f0, acc0, 0, 0, 0);
        acc1 = __builtin_amdgcn_mfma_f32_16x16x32_bf16(a, f1, acc1, 0, 0, 0);
        acc2 = __builtin_amdgcn_mfma_f32_16x16x32_bf16(a, f2, acc2, 0, 0, 0);
        acc3 = __builtin_amdgcn_mfma_f32_16x16x32_bf16(a, f3, acc3, 0, 0, 0);
    }

    float bia0 = b2[r16], bia1 = b2[16 + r16], bia2 = b2[32 + r16], bia3 = b2[48 + r16];

#pragma unroll
    for (int r = 0; r < 4; ++r) {
        int row = base + kg * 4 + r;
        if (row < N) {
            float mmk = (rs[row + 1] > rs[row]) ? 1.f : 0.f;
            float* o = out + (size_t)row * C_OUT;
            o[r16]      = mmk * (acc0[r] + bia0);
            o[16 + r16] = mmk * (acc1[r] + bia1);
            o[32 + r16] = mmk * (acc2[r] + bia2);
            o[48 + r16] = mmk * (acc3[r] + bia3);
        }
    }
}

// ---------------------------------------------------------------------------
extern "C" void kernel_launch(void* const* d_in, const int* in_sizes, int n_in,
                              void* d_out, int out_size, void* d_ws, size_t ws_size,
                              hipStream_t stream) {
    const float* X  = (const float*)d_in[0];
    const float* W1 = (const float*)d_in[1];
    const float* b1 = (const float*)d_in[2];
    const float* W2 = (const float*)d_in[3];
    const float* b2 = (const float*)d_in[4];
    const int*   nbr = (const int*)d_in[5];
    const int*   rs  = (const int*)d_in[6];
    float* outp = (float*)d_out;

    int N = in_sizes[6] - 1;                  // row_splits has N+1 entries
    int E = in_sizes[5];                      // total edges

    // workspace layout (~51.2 MB + 16 KB):
    unsigned*       A16  = (unsigned*)d_ws;                          // N*64 dw
    float*          Bbuf = (float*)(A16 + (size_t)N * (HID / 2));    // N*128 f32
    unsigned*       Hout = (unsigned*)(Bbuf + (size_t)N * HID);      // N*64 dw
    unsigned short* W2T  = (unsigned short*)(Hout + (size_t)N * (HID / 2)); // 8192

    int g1 = (N + K1_NODES - 1) / K1_NODES;
    hipLaunchKernelGGL(precompute_ab, dim3(g1), dim3(512), 0, stream,
                       X, W1, b1, W2, A16, Bbuf, W2T, N);

    int G = 12288;
    hipLaunchKernelGGL(edge_agg, dim3(G), dim3(128), 0, stream,
                       A16, Bbuf, nbr, rs, Hout, N, E, G);

    int stripes = (N + 15) / 16;
    int g3 = (stripes + 3) / 4;
    hipLaunchKernelGGL(h_w2_mfma, dim3(g3), dim3(256), 0, stream,
                       (const unsigned short*)Hout, W2T, b2, rs, outp, N);
}

// Round 2
// 129.269 us; speedup vs baseline: 1.1345x; 1.0360x over previous
//
#include <hip/hip_runtime.h>
#include <hip/hip_bf16.h>
#include <math.h>

#define C_IN  64
#define HID   128
#define C_OUT 64

typedef __attribute__((ext_vector_type(8))) short s16x8;   // 8 bf16 (4 VGPR)
typedef __attribute__((ext_vector_type(4))) float f32x4;   // MFMA acc
typedef __attribute__((ext_vector_type(2))) float f32x2;   // packed-fp32 pair

// ---------------------------------------------------------------------------
// Fast GELU (tanh form), PACKED 2-wide. Bit-identical math to prior rounds.
// ---------------------------------------------------------------------------
__device__ __forceinline__ f32x2 gelu2(f32x2 x) {
    f32x2 t  = x * x;                                   // pk_mul
    f32x2 p  = t * 0.10294455f + 2.30211462f;           // pk_fma
    f32x2 xp = x * p;                                   // pk_mul
    f32x2 E;
    E.x = __builtin_amdgcn_exp2f(xp.x);                 // trans
    E.y = __builtin_amdgcn_exp2f(xp.y);                 // trans
    f32x2 Ep = E + 1.0f;                                // pk_add
    f32x2 r;
    r.x = __builtin_amdgcn_rcpf(Ep.x);                  // trans
    r.y = __builtin_amdgcn_rcpf(Ep.y);                  // trans
    return x - x * r;                                   // pk_fma
}

__device__ __forceinline__ float4 fma4(float s, float4 w, float4 acc) {
    acc.x = fmaf(s, w.x, acc.x); acc.y = fmaf(s, w.y, acc.y);
    acc.z = fmaf(s, w.z, acc.z); acc.w = fmaf(s, w.w, acc.w);
    return acc;
}

__device__ __forceinline__ unsigned pk_bf16(float lo, float hi) {
    union { __hip_bfloat162 v; unsigned u; } cv;
    cv.v = __float22bfloat162_rn(make_float2(lo, hi));
    return cv.u;
}
// unpack dword of 2x bf16 -> f32x2 (consecutive VGPRs -> pk-friendly)
__device__ __forceinline__ f32x2 unpk2(unsigned p) {
    union { unsigned u; float f; } lo, hi;
    lo.u = p << 16; hi.u = p & 0xffff0000u;
    f32x2 v; v.x = lo.f; v.y = hi.f; return v;
}

// ---------------------------------------------------------------------------
// Kernel 1: per-node factored first linear ([50000x64] @ [64x256] GEMM).
//   A16[n][h] = bf16( X[n][:] . W1[0:64,h] )       (gathered per-edge)
//   B  [n][h] =       X[n][:] . W1[64:128,h] + b1  (read per-row, f32)
// Block 0 additionally transposes W2 -> W2T[c][k] bf16 for the MFMA kernel.
// NEW: first G/512+1 blocks also precompute the edge-balanced block->row
// partition for edge_agg (removes 2x 16-level binary search per block there).
// ---------------------------------------------------------------------------
#define K1_NODES 64

__global__ __launch_bounds__(512, 2) void precompute_ab(
    const float* __restrict__ X, const float* __restrict__ W1,
    const float* __restrict__ b1, const float* __restrict__ W2,
    const int* __restrict__ rs,
    unsigned* __restrict__ A16, float* __restrict__ B,
    unsigned short* __restrict__ W2T, int* __restrict__ bsplit,
    int N, int E, int G)
{
    __shared__ float W1s[2 * C_IN * HID];     // 64 KiB
    __shared__ float xs[K1_NODES * C_IN];     // 16 KiB
    int tid = threadIdx.x;

    for (int i = tid; i < (2 * C_IN * HID) / 4; i += 512)
        ((float4*)W1s)[i] = ((const float4*)W1)[i];

    int base = blockIdx.x * K1_NODES;
    int nLoc = min(K1_NODES, N - base);
    for (int i = tid; i < nLoc * (C_IN / 4); i += 512)
        ((float4*)xs)[i] = ((const float4*)(X + (size_t)base * C_IN))[i];

    if (blockIdx.x == 0) {                     // one-time W2 -> bf16 k-major
        for (int i = tid; i < C_OUT * HID; i += 512) {
            int c = i >> 7, k = i & (HID - 1);
            W2T[i] = (unsigned short)pk_bf16(W2[k * C_OUT + c], 0.f);
        }
    }

    // ---- block->row partition for edge_agg (lane-parallel binary search) ----
    {
        int gi = blockIdx.x * 512 + tid;
        if (gi <= G) {
            int t = (int)(((long long)E * gi) / G);
            int lo = 0, hi = N;
            while (lo < hi) { int mm = (lo + hi) >> 1; if (rs[mm] < t) lo = mm + 1; else hi = mm; }
            bsplit[gi] = lo;
        }
    }

    __syncthreads();

    int quad = (tid & 31) * 4;    // h-quad 0,4,...,124
    int slot = tid >> 5;          // 0..15, owns nodes 4*slot .. 4*slot+3
    int s0   = slot * 4;
    if (s0 >= nLoc) return;

    float4 a0 = {}, a1 = {}, a2 = {}, a3 = {};
    float4 b0 = {}, b1r = {}, b2r = {}, b3 = {};

    const float* xr0 = xs + (s0 + 0) * C_IN;
    const float* xr1 = xs + (s0 + 1) * C_IN;
    const float* xr2 = xs + (s0 + 2) * C_IN;
    const float* xr3 = xs + (s0 + 3) * C_IN;

#define K1STEP(c, CMP)                                                      \
    do {                                                                    \
        float4 wa = *(const float4*)&W1s[(c) * HID + quad];                 \
        float4 wb = *(const float4*)&W1s[((c) + C_IN) * HID + quad];        \
        a0 = fma4(xv0.CMP, wa, a0); b0  = fma4(xv0.CMP, wb, b0);            \
        a1 = fma4(xv1.CMP, wa, a1); b1r = fma4(xv1.CMP, wb, b1r);           \
        a2 = fma4(xv2.CMP, wa, a2); b2r = fma4(xv2.CMP, wb, b2r);           \
        a3 = fma4(xv3.CMP, wa, a3); b3  = fma4(xv3.CMP, wb, b3);            \
    } while (0)

#pragma unroll 1
    for (int c4 = 0; c4 < C_IN; c4 += 4) {
        float4 xv0 = *(const float4*)&xr0[c4];
        float4 xv1 = *(const float4*)&xr1[c4];
        float4 xv2 = *(const float4*)&xr2[c4];
        float4 xv3 = *(const float4*)&xr3[c4];
        K1STEP(c4 + 0, x);
        K1STEP(c4 + 1, y);
        K1STEP(c4 + 2, z);
        K1STEP(c4 + 3, w);
    }
#undef K1STEP

    float4 bb = *(const float4*)(b1 + quad);
    b0.x += bb.x;  b0.y += bb.y;  b0.z += bb.z;  b0.w += bb.w;
    b1r.x += bb.x; b1r.y += bb.y; b1r.z += bb.z; b1r.w += bb.w;
    b2r.x += bb.x; b2r.y += bb.y; b2r.z += bb.z; b2r.w += bb.w;
    b3.x += bb.x;  b3.y += bb.y;  b3.z += bb.z;  b3.w += bb.w;

    int adw = (base + s0) * (HID / 2) + (quad >> 1);
    size_t boff = (size_t)(base + s0) * HID + quad;
    if (s0 + 0 < nLoc) {
        uint2 u = { pk_bf16(a0.x, a0.y), pk_bf16(a0.z, a0.w) };
        *(uint2*)(A16 + adw) = u;              *(float4*)(B + boff) = b0;
    }
    if (s0 + 1 < nLoc) {
        uint2 u = { pk_bf16(a1.x, a1.y), pk_bf16(a1.z, a1.w) };
        *(uint2*)(A16 + adw + HID / 2) = u;    *(float4*)(B + boff + HID) = b1r;
    }
    if (s0 + 2 < nLoc) {
        uint2 u = { pk_bf16(a2.x, a2.y), pk_bf16(a2.z, a2.w) };
        *(uint2*)(A16 + adw + HID) = u;        *(float4*)(B + boff + 2 * HID) = b2r;
    }
    if (s0 + 3 < nLoc) {
        uint2 u = { pk_bf16(a3.x, a3.y), pk_bf16(a3.z, a3.w) };
        *(uint2*)(A16 + adw + 3 * (HID / 2)) = u; *(float4*)(B + boff + 3 * HID) = b3;
    }
}

// ---------------------------------------------------------------------------
// Kernel 2: latency-hiding edge aggregation.
//   * 2 edges per gather instruction (32 lanes/edge, dwordx2/lane).
//   * block row-range read from precomputed bsplit (no binary search).
//   * cross-row + cross-chunk prefetch: next row's rs/B/nbr-chunk loads are
//     issued under the current row's gather+GELU compute.
//   * gathers pipelined 2 groups (16 edges) ahead via 3 static buffers.
// ---------------------------------------------------------------------------
#define EA_WAVES 2

#define EA_ISSUE(P0,P1,P2,P3, g) do { int _s8 = ((g) << 3) + half;            \
    int _i0 = __shfl(idx, _s8);                                               \
    int _i1 = __shfl(idx, _s8 + 2);                                           \
    int _i2 = __shfl(idx, _s8 + 4);                                           \
    int _i3 = __shfl(idx, _s8 + 6);                                           \
    P0 = *(const uint2*)(A8 + ((((unsigned)_i0) << 8) | lb));                 \
    P1 = *(const uint2*)(A8 + ((((unsigned)_i1) << 8) | lb));                 \
    P2 = *(const uint2*)(A8 + ((((unsigned)_i2) << 8) | lb));                 \
    P3 = *(const uint2*)(A8 + ((((unsigned)_i3) << 8) | lb));                 \
} while (0)

#define EA_PROC1(P) do {                                                      \
    acc01 += gelu2(unpk2(P.x) + bb01);                                        \
    acc23 += gelu2(unpk2(P.y) + bb23); } while (0)

#define EA_PROC1M(P, p) do {                                                  \
    float _mk = ((((p) << 1) + half) < m) ? 1.f : 0.f;                        \
    acc01 += gelu2(unpk2(P.x) + bb01) * _mk;                                  \
    acc23 += gelu2(unpk2(P.y) + bb23) * _mk; } while (0)

#define EA_PROCG(P0,P1,P2,P3, g) do {                                         \
    if ((((g) + 1) << 3) <= m) { EA_PROC1(P0); EA_PROC1(P1);                  \
                                 EA_PROC1(P2); EA_PROC1(P3); }                \
    else { int _p = (g) << 2;                                                 \
           EA_PROC1M(P0, _p);                                                 \
           if (((_p + 1) << 1) < m) EA_PROC1M(P1, _p + 1);                    \
           if (((_p + 2) << 1) < m) EA_PROC1M(P2, _p + 2);                    \
           if (((_p + 3) << 1) < m) EA_PROC1M(P3, _p + 3); } } while (0)

__global__ __launch_bounds__(128) void edge_agg(
    const unsigned* __restrict__ A16, const float* __restrict__ B,
    const int* __restrict__ nbr, const int* __restrict__ rs,
    const int* __restrict__ bsplit,
    unsigned* __restrict__ Hout, int N, int E, int G)
{
    int wave = threadIdx.x >> 6, lane = threadIdx.x & 63;
    int half = lane >> 5, l5 = lane & 31;
    const char* A8 = (const char*)A16;
    unsigned lb = (unsigned)(l5 << 3);          // byte offset within row
    int b = blockIdx.x;

    int r0 = bsplit[b];
    int r1 = (b == G - 1) ? N : bsplit[b + 1];

    int row = r0 + wave;
    if (row >= r1) return;

    // prologue: current row meta + first index chunk
    int s = rs[row], e = rs[row + 1];
    float4 bb4 = *(const float4*)(B + (size_t)row * HID + l5 * 4);
    int idx = 0;
    if (e > s) { int mn = min(64, e - s); idx = nbr[s + min(lane, mn - 1)]; }

    for (;;) {
        int cnt = e - s;

        // prefetch next row's meta early (lands under this row's compute)
        int nrow = row + EA_WAVES;
        bool hasn = nrow < r1;
        int sn = s, en = e;
        float4 bbn = bb4;
        if (hasn) {
            sn = rs[nrow]; en = rs[nrow + 1];
            bbn = *(const float4*)(B + (size_t)nrow * HID + l5 * 4);
        }

        f32x2 bb01, bb23;
        bb01.x = bb4.x; bb01.y = bb4.y; bb23.x = bb4.z; bb23.y = bb4.w;
        f32x2 acc01 = {0.f, 0.f}, acc23 = {0.f, 0.f};

        if (cnt > 0) {
            int cs = s;
            for (;;) {                          // chunk loop (64 edges/chunk)
                int m = min(64, e - cs);
                int ng = (m + 7) >> 3;

                uint2 A0, A1, A2, A3, B0, B1, B2, B3, C0, C1, C2, C3;
                EA_ISSUE(A0, A1, A2, A3, 0);
                if (ng > 1) EA_ISSUE(B0, B1, B2, B3, 1);

                // prefetch next index chunk (same row) or next row's chunk 0
                int ncs = cs + 64;
                int idx_next = idx;
                if (ncs < e) {
                    int mn = min(64, e - ncs);
                    idx_next = nbr[ncs + min(lane, mn - 1)];
                } else if (hasn && en > sn) {
                    int mn = min(64, en - sn);
                    idx_next = nbr[sn + min(lane, mn - 1)];
                }

                int g = 0;
                for (;;) {                      // 3-stage rotation, 2 groups ahead
                    if (g + 2 < ng) EA_ISSUE(C0, C1, C2, C3, g + 2);
                    EA_PROCG(A0, A1, A2, A3, g);
                    if (++g >= ng) break;
                    if (g + 2 < ng) EA_ISSUE(A0, A1, A2, A3, g + 2);
                    EA_PROCG(B0, B1, B2, B3, g);
                    if (++g >= ng) break;
                    if (g + 2 < ng) EA_ISSUE(B0, B1, B2, B3, g + 2);
                    EA_PROCG(C0, C1, C2, C3, g);
                    if (++g >= ng) break;
                }

                idx = idx_next;
                if (ncs >= e) break;
                cs = ncs;
            }
        } else if (hasn && en > sn) {           // empty row: keep idx chain alive
            int mn = min(64, en - sn);
            idx = nbr[sn + min(lane, mn - 1)];
        }

        // merge the two half-wave edge partial sums
        acc01.x += __shfl_xor(acc01.x, 32);
        acc01.y += __shfl_xor(acc01.y, 32);
        acc23.x += __shfl_xor(acc23.x, 32);
        acc23.y += __shfl_xor(acc23.y, 32);

        if (half == 0) {
            float sc = (cnt > 0) ? 1.f / (float)cnt : 0.f;
            uint2 o = { pk_bf16(acc01.x * sc, acc01.y * sc),
                        pk_bf16(acc23.x * sc, acc23.y * sc) };
            ((uint2*)(Hout + (size_t)row * (HID / 2)))[l5] = o;
        }

        if (!hasn) break;
        row = nrow; s = sn; e = en; bb4 = bbn;
    }
}

#undef EA_ISSUE
#undef EA_PROC1
#undef EA_PROC1M
#undef EA_PROCG

// ---------------------------------------------------------------------------
// Kernel 3: out = Hbar @ W2 + b2 via MFMA (bf16 in, f32 out). Unchanged.
// ---------------------------------------------------------------------------
__global__ __launch_bounds__(256) void h_w2_mfma(
    const unsigned short* __restrict__ H, const unsigned short* __restrict__ W2T,
    const float* __restrict__ b2, const int* __restrict__ rs,
    float* __restrict__ out, int N)
{
    int wave = threadIdx.x >> 6, lane = threadIdx.x & 63;
    int base = (blockIdx.x * 4 + wave) * 16;
    if (base >= N) return;

    int r16 = lane & 15;
    int kg  = lane >> 4;

    const unsigned short* hrow = H + (size_t)(base + r16) * HID + kg * 8;
    const unsigned short* wc0  = W2T + (size_t)(0 * 16 + r16) * HID + kg * 8;
    const unsigned short* wc1  = W2T + (size_t)(1 * 16 + r16) * HID + kg * 8;
    const unsigned short* wc2  = W2T + (size_t)(2 * 16 + r16) * HID + kg * 8;
    const unsigned short* wc3  = W2T + (size_t)(3 * 16 + r16) * HID + kg * 8;

    f32x4 acc0 = {0.f, 0.f, 0.f, 0.f};
    f32x4 acc1 = acc0, acc2 = acc0, acc3 = acc0;

#pragma unroll
    for (int kk = 0; kk < 4; ++kk) {
        s16x8 a  = *(const s16x8*)(hrow + kk * 32);
        s16x8 f0 = *(const s16x8*)(wc0 + kk * 32);
        s16x8 f1 = *(const s16x8*)(wc1 + kk * 32);
        s16x8 f2 = *(const s16x8*)(wc2 + kk * 32);
        s16x8 f3 = *(const s16x8*)(wc3 + kk * 32);
        acc0 = __builtin_amdgcn_mfma_f32_16x16x32_bf16(a, f0, acc0, 0, 0, 0);
        acc1 = __builtin_amdgcn_mfma_f32_16x16x32_bf16(a, f1, acc1, 0, 0, 0);
        acc2 = __builtin_amdgcn_mfma_f32_16x16x32_bf16(a, f2, acc2, 0, 0, 0);
        acc3 = __builtin_amdgcn_mfma_f32_16x16x32_bf16(a, f3, acc3, 0, 0, 0);
    }

    float bia0 = b2[r16], bia1 = b2[16 + r16], bia2 = b2[32 + r16], bia3 = b2[48 + r16];

#pragma unroll
    for (int r = 0; r < 4; ++r) {
        int row = base + kg * 4 + r;
        if (row < N) {
            float mmk = (rs[row + 1] > rs[row]) ? 1.f : 0.f;
            float* o = out + (size_t)row * C_OUT;
            o[r16]      = mmk * (acc0[r] + bia0);
            o[16 + r16] = mmk * (acc1[r] + bia1);
            o[32 + r16] = mmk * (acc2[r] + bia2);
            o[48 + r16] = mmk * (acc3[r] + bia3);
        }
    }
}

// ---------------------------------------------------------------------------
extern "C" void kernel_launch(void* const* d_in, const int* in_sizes, int n_in,
                              void* d_out, int out_size, void* d_ws, size_t ws_size,
                              hipStream_t stream) {
    const float* X  = (const float*)d_in[0];
    const float* W1 = (const float*)d_in[1];
    const float* b1 = (const float*)d_in[2];
    const float* W2 = (const float*)d_in[3];
    const float* b2 = (const float*)d_in[4];
    const int*   nbr = (const int*)d_in[5];
    const int*   rs  = (const int*)d_in[6];
    float* outp = (float*)d_out;

    int N = in_sizes[6] - 1;                  // row_splits has N+1 entries
    int E = in_sizes[5];                      // total edges

    int G = 12288;

    // workspace layout (~51.3 MB):
    unsigned*       A16  = (unsigned*)d_ws;                          // N*64 dw
    float*          Bbuf = (float*)(A16 + (size_t)N * (HID / 2));    // N*128 f32
    unsigned*       Hout = (unsigned*)(Bbuf + (size_t)N * HID);      // N*64 dw
    unsigned short* W2T  = (unsigned short*)(Hout + (size_t)N * (HID / 2)); // 8192
    int*            bsplit = (int*)(W2T + C_OUT * HID);              // G+1 ints

    int g1 = (N + K1_NODES - 1) / K1_NODES;
    hipLaunchKernelGGL(precompute_ab, dim3(g1), dim3(512), 0, stream,
                       X, W1, b1, W2, rs, A16, Bbuf, W2T, bsplit, N, E, G);

    hipLaunchKernelGGL(edge_agg, dim3(G), dim3(128), 0, stream,
                       A16, Bbuf, nbr, rs, bsplit, Hout, N, E, G);

    int stripes = (N + 15) / 16;
    int g3 = (stripes + 3) / 4;
    hipLaunchKernelGGL(h_w2_mfma, dim3(g3), dim3(256), 0, stream,
                       (const unsigned short*)Hout, W2T, b2, rs, outp, N);
}